// Round 14
// baseline (530.896 us; speedup 1.0000x reference)
//
#include <hip/hip_runtime.h>
#include <hip/hip_bf16.h>

typedef _Float16 half8 __attribute__((ext_vector_type(8)));
typedef float f32x4 __attribute__((ext_vector_type(4)));

#define B_SZ 64
#define T_SZ 512
#define E_SZ 768
#define H_SZ 256
#define V_SZ 3072

// workspace layout (bytes)
#define WS_X     0u          // _Float16 x[T][B][H]           16,777,216 B
#define WS_WT    16777216u   // _Float16 Wt[256][768] (Wxh^T)    393,216 B
#define WS_WF    17170432u   // _Float16 Wf[65536] Whh MFMA-B    131,072 B
#define WS_H     17301504u   // float    h[64][256]               65,536 B

// fast tanh: 1 - 2/(1+exp(2x)); exact at +/-inf, ~1e-6 rel err
static __device__ __forceinline__ float fast_tanh(float x) {
  float e = __builtin_amdgcn_exp2f(x * 2.8853900817779268f); // exp(2x)
  return 1.0f - 2.0f * __builtin_amdgcn_rcpf(1.0f + e);
}

// ---------------- k0: prep f16 weight layouts (small) ----------------
// Wt[h][e] = Wxh[e][h] (k1 B panels).
// Wf = Whh in 16x16x32 MFMA-B fragment order (r7-validated):
//   frag(nt,kt)[lane][j] = Whh[kt*32 + (lane>>4)*8 + j][nt*16 + (lane&15)]
__global__ __launch_bounds__(256) void k0_convert(
    const float* __restrict__ Wxh,
    const float* __restrict__ Whh,
    _Float16* __restrict__ Wt,
    _Float16* __restrict__ Wf)
{
  int gid = blockIdx.x * 256 + threadIdx.x;           // 768 WGs = 196608
  if (gid < E_SZ * H_SZ) {
    int e = gid >> 8, h = gid & 255;
    Wt[h * E_SZ + e] = (_Float16)Wxh[gid];
  }
  if (gid < 65536) {
    int j = gid & 7, lane = (gid >> 3) & 63, kt = (gid >> 9) & 7, nt = gid >> 12;
    int quad = lane >> 4, n16 = lane & 15;
    int row = kt * 32 + quad * 8 + j, col = nt * 16 + n16;
    Wf[gid] = (_Float16)Whh[row * H_SZ + col];
  }
}

// ---------------- k1: x[t,b,:] = emb[idx[b,t],:] @ Wxh  (MFMA f16) ----------------
// Double-buffered B panel: ONE barrier per ki.
__global__ __launch_bounds__(256) void k1_xproj(
    const int* __restrict__ idx,
    const float* __restrict__ emb,
    const _Float16* __restrict__ Wt,
    _Float16* __restrict__ x)
{
  const int tid  = threadIdx.x;
  const int w    = tid >> 6;
  const int lane = tid & 63;
  const int m16  = lane & 15;
  const int quad = lane >> 4;
  const int r = blockIdx.x * 64 + w * 16 + m16;     // row in [T*B], r = t*64 + b
  const int t = r >> 6;
  const int b = r & 63;
  const int erow = idx[b * T_SZ + t];
  const float* Arow = emb + (size_t)erow * E_SZ + quad * 8;   // A[m][k=quad*8+j]

  __shared__ __align__(16) _Float16 bp[2][16 * 64 * 8]; // 2 x 16KB fragment panels
  int n_[4], kb_[4];
#pragma unroll
  for (int pp = 0; pp < 4; ++pp) {
    int f = tid + 256 * pp;
    n_[pp]  = ((f >> 6) << 4) | (f & 15);
    kb_[pp] = (f >> 4) & 3;
  }
  uint4 stg[4];
#pragma unroll
  for (int pp = 0; pp < 4; ++pp)
    stg[pp] = *(const uint4*)(Wt + (size_t)n_[pp] * E_SZ + kb_[pp] * 8);
  f32x4 af0 = *(const f32x4*)(Arow);
  f32x4 af1 = *(const f32x4*)(Arow + 4);

  f32x4 acc[16];
#pragma unroll
  for (int n = 0; n < 16; ++n) { f32x4 z = {0.f, 0.f, 0.f, 0.f}; acc[n] = z; }

  // stage panel 0
#pragma unroll
  for (int pp = 0; pp < 4; ++pp)
    *(uint4*)(bp[0] + (size_t)(tid + 256 * pp) * 8) = stg[pp];
  __syncthreads();

#pragma unroll 1
  for (int ki = 0; ki < 24; ++ki) {
    const _Float16* cur = bp[ki & 1];
    f32x4 af0n = af0, af1n = af1;
    if (ki < 23) {                            // prefetch next panel + next A
#pragma unroll
      for (int pp = 0; pp < 4; ++pp)
        stg[pp] = *(const uint4*)(Wt + (size_t)n_[pp] * E_SZ + (ki + 1) * 32 + kb_[pp] * 8);
      af0n = *(const f32x4*)(Arow + (ki + 1) * 32);
      af1n = *(const f32x4*)(Arow + (ki + 1) * 32 + 4);
    }
    half8 a;
#pragma unroll
    for (int e = 0; e < 4; ++e) { a[e] = (_Float16)af0[e]; a[4 + e] = (_Float16)af1[e]; }
#pragma unroll
    for (int nt = 0; nt < 16; ++nt) {
      half8 bb = *(const half8*)(cur + (size_t)(nt * 64 + lane) * 8);
      acc[nt] = __builtin_amdgcn_mfma_f32_16x16x32_f16(a, bb, acc[nt], 0, 0, 0);
    }
    if (ki < 23) {                            // write next buffer, one barrier
#pragma unroll
      for (int pp = 0; pp < 4; ++pp)
        *(uint4*)(bp[(ki + 1) & 1] + (size_t)(tid + 256 * pp) * 8) = stg[pp];
      __syncthreads();
    }
    af0 = af0n; af1 = af1n;
  }
  const int rbase = blockIdx.x * 64 + w * 16 + quad * 4;  // C/D: col=lane&15, row=quad*4+reg
#pragma unroll
  for (int nt = 0; nt < 16; ++nt) {
    const int col = nt * 16 + m16;
#pragma unroll
    for (int rg = 0; rg < 4; ++rg) {
      x[(size_t)(rbase + rg) * H_SZ + col] = (_Float16)acc[nt][rg];
    }
  }
}

// ---------------- k2: MFMA recurrence, TWO batches per WG interleaved --------
// Grid 32: WG g owns batches 2g,2g+1 — two independent dependence chains share
// the parked Whh AGPRs and one barrier. Batch B's ds_reads issue under batch
// A's 620-cyc MFMA pipe; A's tanh/write fills B's MFMA issue gaps. Static LDS
// offsets (r12 showed runtime rotation regresses). s_nops guard MFMA->VALU.
#define LDFRAG(C, KT, R0, R1, R2, R3) { \
  uint4 q = Wf4[(((size_t)(w * 4 + C) * 8 + KT) * 64) + lane]; \
  asm volatile("v_accvgpr_write_b32 a" #R0 ", %0" :: "v"(q.x) : "a" #R0); \
  asm volatile("v_accvgpr_write_b32 a" #R1 ", %0" :: "v"(q.y) : "a" #R1); \
  asm volatile("v_accvgpr_write_b32 a" #R2 ", %0" :: "v"(q.z) : "a" #R2); \
  asm volatile("v_accvgpr_write_b32 a" #R3 ", %0" :: "v"(q.w) : "a" #R3); }

#define MFMA_K0(A0, Z, C0, C1, C2, C3) \
  asm volatile( \
    "v_mfma_f32_16x16x32_f16 %[t0], %[a], a[0:3],   %[z]\n\t" \
    "v_mfma_f32_16x16x32_f16 %[t1], %[a], a[32:35], %[z]\n\t" \
    "v_mfma_f32_16x16x32_f16 %[t2], %[a], a[64:67], %[z]\n\t" \
    "v_mfma_f32_16x16x32_f16 %[t3], %[a], a[96:99], %[z]" \
    : [t0] "=&v"(C0), [t1] "=&v"(C1), [t2] "=&v"(C2), [t3] "=&v"(C3) \
    : [a] "v"(A0), [z] "v"(Z));

#define MFMA_KT(A0, B0, B1, B2, B3, C0, C1, C2, C3) \
  asm volatile( \
    "v_mfma_f32_16x16x32_f16 %[t0], %[a], a[" #B0 "], %[t0]\n\t" \
    "v_mfma_f32_16x16x32_f16 %[t1], %[a], a[" #B1 "], %[t1]\n\t" \
    "v_mfma_f32_16x16x32_f16 %[t2], %[a], a[" #B2 "], %[t2]\n\t" \
    "v_mfma_f32_16x16x32_f16 %[t3], %[a], a[" #B3 "], %[t3]" \
    : [t0] "+v"(C0), [t1] "+v"(C1), [t2] "+v"(C2), [t3] "+v"(C3) \
    : [a] "v"(A0));

#define MFMA_K7(A0, B0, B1, B2, B3, C0, C1, C2, C3) \
  asm volatile( \
    "v_mfma_f32_16x16x32_f16 %[t0], %[a], a[" #B0 "], %[t0]\n\t" \
    "v_mfma_f32_16x16x32_f16 %[t1], %[a], a[" #B1 "], %[t1]\n\t" \
    "v_mfma_f32_16x16x32_f16 %[t2], %[a], a[" #B2 "], %[t2]\n\t" \
    "v_mfma_f32_16x16x32_f16 %[t3], %[a], a[" #B3 "], %[t3]\n\t" \
    "s_nop 7\n\t" \
    "s_nop 7" \
    : [t0] "+v"(C0), [t1] "+v"(C1), [t2] "+v"(C2), [t3] "+v"(C3) \
    : [a] "v"(A0));

#define MFMA_GROUP(V0,V1,V2,V3,V4,V5,V6,V7, C0,C1,C2,C3, Z) \
  MFMA_K0(V0, Z, C0,C1,C2,C3) \
  MFMA_KT(V1,   4:7,  36:39,  68:71, 100:103, C0,C1,C2,C3) \
  MFMA_KT(V2,  8:11,  40:43,  72:75, 104:107, C0,C1,C2,C3) \
  MFMA_KT(V3, 12:15,  44:47,  76:79, 108:111, C0,C1,C2,C3) \
  MFMA_KT(V4, 16:19,  48:51,  80:83, 112:115, C0,C1,C2,C3) \
  MFMA_KT(V5, 20:23,  52:55,  84:87, 116:119, C0,C1,C2,C3) \
  MFMA_KT(V6, 24:27,  56:59,  88:91, 120:123, C0,C1,C2,C3) \
  MFMA_K7(V7, 28:31,  60:63,  92:95, 124:127, C0,C1,C2,C3)

__global__ __launch_bounds__(256) void k2_rnn(
    const _Float16* __restrict__ Wf,
    const _Float16* __restrict__ x,
    const float* __restrict__ Bh,
    float* __restrict__ hout,
    float* __restrict__ hidout)
{
  const int b0   = blockIdx.x * 2;
  const int b1   = b0 + 1;
  const int tid  = threadIdx.x;
  const int w    = tid >> 6;
  const int lane = tid & 63;
  const int quad = lane >> 4;
  __shared__ __align__(16) _Float16 hb[2][2][H_SZ]; // [buf][batch][col]
  const uint4* Wf4 = (const uint4*)Wf;

  LDFRAG(0,0,  0,  1,  2,  3)  LDFRAG(0,1,  4,  5,  6,  7)
  LDFRAG(0,2,  8,  9, 10, 11)  LDFRAG(0,3, 12, 13, 14, 15)
  LDFRAG(0,4, 16, 17, 18, 19)  LDFRAG(0,5, 20, 21, 22, 23)
  LDFRAG(0,6, 24, 25, 26, 27)  LDFRAG(0,7, 28, 29, 30, 31)
  LDFRAG(1,0, 32, 33, 34, 35)  LDFRAG(1,1, 36, 37, 38, 39)
  LDFRAG(1,2, 40, 41, 42, 43)  LDFRAG(1,3, 44, 45, 46, 47)
  LDFRAG(1,4, 48, 49, 50, 51)  LDFRAG(1,5, 52, 53, 54, 55)
  LDFRAG(1,6, 56, 57, 58, 59)  LDFRAG(1,7, 60, 61, 62, 63)
  LDFRAG(2,0, 64, 65, 66, 67)  LDFRAG(2,1, 68, 69, 70, 71)
  LDFRAG(2,2, 72, 73, 74, 75)  LDFRAG(2,3, 76, 77, 78, 79)
  LDFRAG(2,4, 80, 81, 82, 83)  LDFRAG(2,5, 84, 85, 86, 87)
  LDFRAG(2,6, 88, 89, 90, 91)  LDFRAG(2,7, 92, 93, 94, 95)
  LDFRAG(3,0, 96, 97, 98, 99)  LDFRAG(3,1,100,101,102,103)
  LDFRAG(3,2,104,105,106,107)  LDFRAG(3,3,108,109,110,111)
  LDFRAG(3,4,112,113,114,115)  LDFRAG(3,5,116,117,118,119)
  LDFRAG(3,6,120,121,122,123)  LDFRAG(3,7,124,125,126,127)

  const float bhj = Bh[tid];
  const _Float16* xp0 = x + b0 * H_SZ + tid;
  const _Float16* xp1 = x + b1 * H_SZ + tid;
  _Float16 xq0 = xp0[0], xq1 = xp1[0];
  f32x4 zero4 = {0.f, 0.f, 0.f, 0.f};
  asm volatile("" : "+v"(zero4));        // pin: no remat-mov adjacent to MFMA srcC
  hb[1][0][tid] = (_Float16)0.f;         // t=0 reads buffer 1 = zeros
  hb[1][1][tid] = (_Float16)0.f;
  float h0 = 0.f, h1 = 0.f;
  __syncthreads();

#pragma unroll 1
  for (int t = 0; t < T_SZ; ++t) {
    const int tn = (t < T_SZ - 1) ? (t + 1) : t;
    _Float16 xn0 = xp0[(size_t)tn * (B_SZ * H_SZ)];
    _Float16 xn1 = xp1[(size_t)tn * (B_SZ * H_SZ)];
    const _Float16* hr0 = hb[(t + 1) & 1][0];
    const _Float16* hr1 = hb[(t + 1) & 1][1];
    // A fragments, both batches: static immediate offsets (quad-broadcast)
    half8 va0 = *(const half8*)(hr0 +   0 + quad * 8);
    half8 va1 = *(const half8*)(hr0 +  32 + quad * 8);
    half8 va2 = *(const half8*)(hr0 +  64 + quad * 8);
    half8 va3 = *(const half8*)(hr0 +  96 + quad * 8);
    half8 va4 = *(const half8*)(hr0 + 128 + quad * 8);
    half8 va5 = *(const half8*)(hr0 + 160 + quad * 8);
    half8 va6 = *(const half8*)(hr0 + 192 + quad * 8);
    half8 va7 = *(const half8*)(hr0 + 224 + quad * 8);
    half8 vb0 = *(const half8*)(hr1 +   0 + quad * 8);
    half8 vb1 = *(const half8*)(hr1 +  32 + quad * 8);
    half8 vb2 = *(const half8*)(hr1 +  64 + quad * 8);
    half8 vb3 = *(const half8*)(hr1 +  96 + quad * 8);
    half8 vb4 = *(const half8*)(hr1 + 128 + quad * 8);
    half8 vb5 = *(const half8*)(hr1 + 160 + quad * 8);
    half8 vb6 = *(const half8*)(hr1 + 192 + quad * 8);
    half8 vb7 = *(const half8*)(hr1 + 224 + quad * 8);
    f32x4 ac0, ac1, ac2, ac3, bc0, bc1, bc2, bc3;
    MFMA_GROUP(va0,va1,va2,va3,va4,va5,va6,va7, ac0,ac1,ac2,ac3, zero4)
    MFMA_GROUP(vb0,vb1,vb2,vb3,vb4,vb5,vb6,vb7, bc0,bc1,bc2,bc3, zero4)
    // batch A epilogue (overlaps batch B's MFMA pipe drain)
    {
      float v0 = ac0[0], v1 = ac1[0], v2 = ac2[0], v3 = ac3[0];
      float ylo = (quad & 1) ? v1 : v0;
      float yhi = (quad & 1) ? v3 : v2;
      float y   = (quad & 2) ? yhi : ylo;
      h0 = fast_tanh(y + (float)xq0 + bhj);
      hb[t & 1][0][tid] = (_Float16)h0;
    }
    {
      float v0 = bc0[0], v1 = bc1[0], v2 = bc2[0], v3 = bc3[0];
      float ylo = (quad & 1) ? v1 : v0;
      float yhi = (quad & 1) ? v3 : v2;
      float y   = (quad & 2) ? yhi : ylo;
      h1 = fast_tanh(y + (float)xq1 + bhj);
      hb[t & 1][1][tid] = (_Float16)h1;
    }
    __syncthreads();
    xq0 = xn0; xq1 = xn1;
  }
  hout[b0 * H_SZ + tid] = h0;
  hout[b1 * H_SZ + tid] = h1;
  hidout[b0 * H_SZ + tid] = h0;
  hidout[b1 * H_SZ + tid] = h1;
}

// ---------------- k3: out = hidden @ Wy + By  (all f32) ----------------
__global__ __launch_bounds__(256) void k3_out(
    const float* __restrict__ h,
    const float* __restrict__ Wy,
    const float* __restrict__ By,
    float* __restrict__ out)
{
  __shared__ float hs[H_SZ];
  const int c = blockIdx.x;   // vocab chunk
  const int b = blockIdx.y;   // batch
  const int v = c * 256 + threadIdx.x;
  hs[threadIdx.x] = h[b * H_SZ + threadIdx.x];
  __syncthreads();
  float acc = By[v];
#pragma unroll 8
  for (int jj = 0; jj < H_SZ; ++jj) {
    acc += hs[jj] * Wy[(size_t)jj * V_SZ + v];
  }
  out[(size_t)b * V_SZ + v] = acc;
}

extern "C" void kernel_launch(void* const* d_in, const int* in_sizes, int n_in,
                              void* d_out, int out_size, void* d_ws, size_t ws_size,
                              hipStream_t stream)
{
  const int*   idx = (const int*)d_in[0];
  const float* emb = (const float*)d_in[1];
  const float* Wxh = (const float*)d_in[2];
  const float* Whh = (const float*)d_in[3];
  const float* Wy  = (const float*)d_in[4];
  const float* By  = (const float*)d_in[5];
  const float* Bh  = (const float*)d_in[6];

  char* ws = (char*)d_ws;
  _Float16* x    = (_Float16*)(ws + WS_X);
  _Float16* Wt   = (_Float16*)(ws + WS_WT);
  _Float16* Wf   = (_Float16*)(ws + WS_WF);
  float*    hbuf = (float*)(ws + WS_H);

  float* out    = (float*)d_out;
  float* hidout = out + (size_t)B_SZ * V_SZ;

  k0_convert<<<768, 256, 0, stream>>>(Wxh, Whh, Wt, Wf);
  k1_xproj  <<<512, 256, 0, stream>>>(idx, emb, Wt, x);
  k2_rnn    <<<32, 256, 0, stream>>>(Wf, x, Bh, hbuf, hidout);
  k3_out    <<<dim3(12, 64), 256, 0, stream>>>(hbuf, Wy, By, out);
}

// Round 15
// 387.637 us; speedup vs baseline: 1.3696x; 1.3696x over previous
//
#include <hip/hip_runtime.h>
#include <hip/hip_bf16.h>

typedef _Float16 half8 __attribute__((ext_vector_type(8)));
typedef float f32x4 __attribute__((ext_vector_type(4)));

#define B_SZ 64
#define T_SZ 512
#define E_SZ 768
#define H_SZ 256
#define V_SZ 3072

// workspace layout (bytes)
#define WS_X     0u          // _Float16 x[T][B][H]           16,777,216 B
#define WS_WT    16777216u   // _Float16 Wt[256][768] (Wxh^T)    393,216 B
#define WS_WF    17170432u   // _Float16 Wf[65536] Whh MFMA-B    131,072 B
#define WS_H     17301504u   // float    h[64][256]               65,536 B

// fast tanh: 1 - 2/(1+exp(2x)); exact at +/-inf, ~1e-6 rel err
static __device__ __forceinline__ float fast_tanh(float x) {
  float e = __builtin_amdgcn_exp2f(x * 2.8853900817779268f); // exp(2x)
  return 1.0f - 2.0f * __builtin_amdgcn_rcpf(1.0f + e);
}

// ---------------- k0: prep f16 weight layouts (small) ----------------
// Wt[h][e] = Wxh[e][h] (k1 B panels).
// Wf = Whh in 16x16x32 MFMA-B fragment order (r7-validated):
//   frag(nt,kt)[lane][j] = Whh[kt*32 + (lane>>4)*8 + j][nt*16 + (lane&15)]
__global__ __launch_bounds__(256) void k0_convert(
    const float* __restrict__ Wxh,
    const float* __restrict__ Whh,
    _Float16* __restrict__ Wt,
    _Float16* __restrict__ Wf)
{
  int gid = blockIdx.x * 256 + threadIdx.x;           // 768 WGs = 196608
  if (gid < E_SZ * H_SZ) {
    int e = gid >> 8, h = gid & 255;
    Wt[h * E_SZ + e] = (_Float16)Wxh[gid];
  }
  if (gid < 65536) {
    int j = gid & 7, lane = (gid >> 3) & 63, kt = (gid >> 9) & 7, nt = gid >> 12;
    int quad = lane >> 4, n16 = lane & 15;
    int row = kt * 32 + quad * 8 + j, col = nt * 16 + n16;
    Wf[gid] = (_Float16)Whh[row * H_SZ + col];
  }
}

// ---------------- k1: x[t,b,:] = emb[idx[b,t],:] @ Wxh  (MFMA f16) ----------------
// Double-buffered B panel: ONE barrier per ki.
__global__ __launch_bounds__(256) void k1_xproj(
    const int* __restrict__ idx,
    const float* __restrict__ emb,
    const _Float16* __restrict__ Wt,
    _Float16* __restrict__ x)
{
  const int tid  = threadIdx.x;
  const int w    = tid >> 6;
  const int lane = tid & 63;
  const int m16  = lane & 15;
  const int quad = lane >> 4;
  const int r = blockIdx.x * 64 + w * 16 + m16;     // row in [T*B], r = t*64 + b
  const int t = r >> 6;
  const int b = r & 63;
  const int erow = idx[b * T_SZ + t];
  const float* Arow = emb + (size_t)erow * E_SZ + quad * 8;   // A[m][k=quad*8+j]

  __shared__ __align__(16) _Float16 bp[2][16 * 64 * 8]; // 2 x 16KB fragment panels
  int n_[4], kb_[4];
#pragma unroll
  for (int pp = 0; pp < 4; ++pp) {
    int f = tid + 256 * pp;
    n_[pp]  = ((f >> 6) << 4) | (f & 15);
    kb_[pp] = (f >> 4) & 3;
  }
  uint4 stg[4];
#pragma unroll
  for (int pp = 0; pp < 4; ++pp)
    stg[pp] = *(const uint4*)(Wt + (size_t)n_[pp] * E_SZ + kb_[pp] * 8);
  f32x4 af0 = *(const f32x4*)(Arow);
  f32x4 af1 = *(const f32x4*)(Arow + 4);

  f32x4 acc[16];
#pragma unroll
  for (int n = 0; n < 16; ++n) { f32x4 z = {0.f, 0.f, 0.f, 0.f}; acc[n] = z; }

  // stage panel 0
#pragma unroll
  for (int pp = 0; pp < 4; ++pp)
    *(uint4*)(bp[0] + (size_t)(tid + 256 * pp) * 8) = stg[pp];
  __syncthreads();

#pragma unroll 1
  for (int ki = 0; ki < 24; ++ki) {
    const _Float16* cur = bp[ki & 1];
    f32x4 af0n = af0, af1n = af1;
    if (ki < 23) {                            // prefetch next panel + next A
#pragma unroll
      for (int pp = 0; pp < 4; ++pp)
        stg[pp] = *(const uint4*)(Wt + (size_t)n_[pp] * E_SZ + (ki + 1) * 32 + kb_[pp] * 8);
      af0n = *(const f32x4*)(Arow + (ki + 1) * 32);
      af1n = *(const f32x4*)(Arow + (ki + 1) * 32 + 4);
    }
    half8 a;
#pragma unroll
    for (int e = 0; e < 4; ++e) { a[e] = (_Float16)af0[e]; a[4 + e] = (_Float16)af1[e]; }
#pragma unroll
    for (int nt = 0; nt < 16; ++nt) {
      half8 bb = *(const half8*)(cur + (size_t)(nt * 64 + lane) * 8);
      acc[nt] = __builtin_amdgcn_mfma_f32_16x16x32_f16(a, bb, acc[nt], 0, 0, 0);
    }
    if (ki < 23) {                            // write next buffer, one barrier
#pragma unroll
      for (int pp = 0; pp < 4; ++pp)
        *(uint4*)(bp[(ki + 1) & 1] + (size_t)(tid + 256 * pp) * 8) = stg[pp];
      __syncthreads();
    }
    af0 = af0n; af1 = af1n;
  }
  const int rbase = blockIdx.x * 64 + w * 16 + quad * 4;  // C/D: col=lane&15, row=quad*4+reg
#pragma unroll
  for (int nt = 0; nt < 16; ++nt) {
    const int col = nt * 16 + m16;
#pragma unroll
    for (int rg = 0; rg < 4; ++rg) {
      x[(size_t)(rbase + rg) * H_SZ + col] = (_Float16)acc[nt][rg];
    }
  }
}

// ---------------- k2: MFMA recurrence, 8 waves/WG (2 waves per SIMD) --------
// One batch per WG, grid 64 (all 64 CUs). 512 threads = 8 waves; wave w owns
// N-tiles 2w,2w+1 -> 16 MFMAs/step with B parked in 64 AGPRs. Per-SIMD MFMA
// issue stays at the 620-cyc floor (2 waves x 16), but each wave's overhead
// (post-barrier ds_read latency, tanh, barrier drain) now overlaps the OTHER
// wave's MFMA issue on the same SIMD (m114 co-scheduling). r14's mistake --
// both chains in one wave -- doubled the serial issue floor instead.
#define LDFRAG(C, KT, R0, R1, R2, R3) { \
  uint4 q = Wf4[(((size_t)(w * 2 + C) * 8 + KT) * 64) + lane]; \
  asm volatile("v_accvgpr_write_b32 a" #R0 ", %0" :: "v"(q.x) : "a" #R0); \
  asm volatile("v_accvgpr_write_b32 a" #R1 ", %0" :: "v"(q.y) : "a" #R1); \
  asm volatile("v_accvgpr_write_b32 a" #R2 ", %0" :: "v"(q.z) : "a" #R2); \
  asm volatile("v_accvgpr_write_b32 a" #R3 ", %0" :: "v"(q.w) : "a" #R3); }

#define MFMA_K0(A0, Z) \
  asm volatile( \
    "v_mfma_f32_16x16x32_f16 %[t0], %[a], a[0:3],   %[z]\n\t" \
    "v_mfma_f32_16x16x32_f16 %[t1], %[a], a[32:35], %[z]" \
    : [t0] "=&v"(acc0), [t1] "=&v"(acc1) \
    : [a] "v"(A0), [z] "v"(Z));

#define MFMA_KT(A0, B0, B1) \
  asm volatile( \
    "v_mfma_f32_16x16x32_f16 %[t0], %[a], a[" #B0 "], %[t0]\n\t" \
    "v_mfma_f32_16x16x32_f16 %[t1], %[a], a[" #B1 "], %[t1]" \
    : [t0] "+v"(acc0), [t1] "+v"(acc1) \
    : [a] "v"(A0));

#define MFMA_K7(A0, B0, B1) \
  asm volatile( \
    "v_mfma_f32_16x16x32_f16 %[t0], %[a], a[" #B0 "], %[t0]\n\t" \
    "v_mfma_f32_16x16x32_f16 %[t1], %[a], a[" #B1 "], %[t1]\n\t" \
    "s_nop 7\n\t" \
    "s_nop 7" \
    : [t0] "+v"(acc0), [t1] "+v"(acc1) \
    : [a] "v"(A0));

__global__ __launch_bounds__(512) void k2_rnn(
    const _Float16* __restrict__ Wf,
    const _Float16* __restrict__ x,
    const float* __restrict__ Bh,
    float* __restrict__ hout,
    float* __restrict__ hidout)
{
  const int b    = blockIdx.x;
  const int tid  = threadIdx.x;
  const int w    = tid >> 6;          // wave 0..7
  const int lane = tid & 63;
  const int quad = lane >> 4;
  const int n16  = lane & 15;
  __shared__ __align__(16) _Float16 hb[2][H_SZ];   // h as f16, double-buffered
  const uint4* Wf4 = (const uint4*)Wf;

  // park 16 B-frags: nt=2w slots -> a0..a31, nt=2w+1 -> a32..a63
  LDFRAG(0,0,  0,  1,  2,  3)  LDFRAG(0,1,  4,  5,  6,  7)
  LDFRAG(0,2,  8,  9, 10, 11)  LDFRAG(0,3, 12, 13, 14, 15)
  LDFRAG(0,4, 16, 17, 18, 19)  LDFRAG(0,5, 20, 21, 22, 23)
  LDFRAG(0,6, 24, 25, 26, 27)  LDFRAG(0,7, 28, 29, 30, 31)
  LDFRAG(1,0, 32, 33, 34, 35)  LDFRAG(1,1, 36, 37, 38, 39)
  LDFRAG(1,2, 40, 41, 42, 43)  LDFRAG(1,3, 44, 45, 46, 47)
  LDFRAG(1,4, 48, 49, 50, 51)  LDFRAG(1,5, 52, 53, 54, 55)
  LDFRAG(1,6, 56, 57, 58, 59)  LDFRAG(1,7, 60, 61, 62, 63)

  const int col0 = w * 32 + n16;            // nt = 2w
  const int col1 = col0 + 16;               // nt = 2w+1
  const float bh0 = Bh[col0];
  const float bh1 = Bh[col1];
  const _Float16* xp0 = x + b * H_SZ + col0;
  const _Float16* xp1 = x + b * H_SZ + col1;
  _Float16 xq0 = xp0[0], xq1 = xp1[0];
  f32x4 zero4 = {0.f, 0.f, 0.f, 0.f};
  asm volatile("" : "+v"(zero4));        // pin: no remat-mov adjacent to MFMA srcC
  if (tid < H_SZ) hb[1][tid] = (_Float16)0.f;   // t=0 reads buffer 1 = zeros
  float h0 = 0.f, h1 = 0.f;
  __syncthreads();

#pragma unroll 1
  for (int t = 0; t < T_SZ; ++t) {
    const int tn = (t < T_SZ - 1) ? (t + 1) : t;
    _Float16 xn0 = xp0[(size_t)tn * (B_SZ * H_SZ)];   // prefetch next x
    _Float16 xn1 = xp1[(size_t)tn * (B_SZ * H_SZ)];
    const _Float16* hr = hb[(t + 1) & 1];
    // A fragments: h[kt*32+quad*8 .. +7], rows replicated (quad-broadcast)
    half8 va0 = *(const half8*)(hr +   0 + quad * 8);
    half8 va1 = *(const half8*)(hr +  32 + quad * 8);
    half8 va2 = *(const half8*)(hr +  64 + quad * 8);
    half8 va3 = *(const half8*)(hr +  96 + quad * 8);
    half8 va4 = *(const half8*)(hr + 128 + quad * 8);
    half8 va5 = *(const half8*)(hr + 160 + quad * 8);
    half8 va6 = *(const half8*)(hr + 192 + quad * 8);
    half8 va7 = *(const half8*)(hr + 224 + quad * 8);
    f32x4 acc0, acc1;
    MFMA_K0(va0, zero4)
    MFMA_KT(va1,  4:7,  36:39)
    MFMA_KT(va2,  8:11, 40:43)
    MFMA_KT(va3, 12:15, 44:47)
    MFMA_KT(va4, 16:19, 48:51)
    MFMA_KT(va5, 20:23, 52:55)
    MFMA_KT(va6, 24:27, 56:59)
    MFMA_K7(va7, 28:31, 60:63)
    // D rows all identical (A rows replicated) -> acc[0] valid in every lane
    h0 = fast_tanh(acc0[0] + (float)xq0 + bh0);
    h1 = fast_tanh(acc1[0] + (float)xq1 + bh1);
    if (quad == 0) {                        // 4-fold quad redundancy: one writes
      hb[t & 1][col0] = (_Float16)h0;
      hb[t & 1][col1] = (_Float16)h1;
    }
    __syncthreads();
    xq0 = xn0; xq1 = xn1;
  }
  if (quad == 0) {
    hout[b * H_SZ + col0] = h0;  hout[b * H_SZ + col1] = h1;
    hidout[b * H_SZ + col0] = h0; hidout[b * H_SZ + col1] = h1;
  }
}

// ---------------- k3: out = hidden @ Wy + By  (all f32) ----------------
__global__ __launch_bounds__(256) void k3_out(
    const float* __restrict__ h,
    const float* __restrict__ Wy,
    const float* __restrict__ By,
    float* __restrict__ out)
{
  __shared__ float hs[H_SZ];
  const int c = blockIdx.x;   // vocab chunk
  const int b = blockIdx.y;   // batch
  const int v = c * 256 + threadIdx.x;
  hs[threadIdx.x] = h[b * H_SZ + threadIdx.x];
  __syncthreads();
  float acc = By[v];
#pragma unroll 8
  for (int jj = 0; jj < H_SZ; ++jj) {
    acc += hs[jj] * Wy[(size_t)jj * V_SZ + v];
  }
  out[(size_t)b * V_SZ + v] = acc;
}

extern "C" void kernel_launch(void* const* d_in, const int* in_sizes, int n_in,
                              void* d_out, int out_size, void* d_ws, size_t ws_size,
                              hipStream_t stream)
{
  const int*   idx = (const int*)d_in[0];
  const float* emb = (const float*)d_in[1];
  const float* Wxh = (const float*)d_in[2];
  const float* Whh = (const float*)d_in[3];
  const float* Wy  = (const float*)d_in[4];
  const float* By  = (const float*)d_in[5];
  const float* Bh  = (const float*)d_in[6];

  char* ws = (char*)d_ws;
  _Float16* x    = (_Float16*)(ws + WS_X);
  _Float16* Wt   = (_Float16*)(ws + WS_WT);
  _Float16* Wf   = (_Float16*)(ws + WS_WF);
  float*    hbuf = (float*)(ws + WS_H);

  float* out    = (float*)d_out;
  float* hidout = out + (size_t)B_SZ * V_SZ;

  k0_convert<<<768, 256, 0, stream>>>(Wxh, Whh, Wt, Wf);
  k1_xproj  <<<512, 256, 0, stream>>>(idx, emb, Wt, x);
  k2_rnn    <<<64, 512, 0, stream>>>(Wf, x, Bh, hbuf, hidout);
  k3_out    <<<dim3(12, 64), 256, 0, stream>>>(hbuf, Wy, By, out);
}